// Round 9
// baseline (919.219 us; speedup 1.0000x reference)
//
#include <hip/hip_runtime.h>
#include <cstddef>
#include <cstdint>

#define NNODES 8192
#define BATCH  16
#define HID    64
#define NEDGE  131072
#define SN     524288   // NNODES * HID (per-batch state stride)
#define OUTHALF 8388608 // BATCH * SN
#define FP2    72       // padded per-slab feature dim (66 real + 6 zero)
#define KP2    384      // padded K' = 12 k-tiles of 32 (360 real + 24 zero)
#define GN     4        // nodes per GEMM block (2048 blocks)

// ---- slice-major slab geometry: slab = [slice(8)][node(8192)][144 ushorts] ----
#define CHUS   144              // ushorts per (slice,node) chunk (288 B)
#define CHU4   18               // uint4 per chunk
#define SLAB_SL 1179648         // ushorts per slice region (8192*144)
#define SLABT  9437184          // ushorts per slab (8*SLAB_SL)
#define SLAB4  1179648          // uint4 per slab (SLABT/8)

typedef __attribute__((ext_vector_type(8))) short bf16x8;
typedef __attribute__((ext_vector_type(4))) float f32x4;

static __device__ __forceinline__ float bf2f(ushort u) {
    union { uint32_t i; float f; } c; c.i = ((uint32_t)u) << 16; return c.f;
}
static __device__ __forceinline__ ushort f2bf(float f) {
    union { float f; uint32_t i; } c; c.f = f;
    uint32_t lsb = (c.i >> 16) & 1;
    return (ushort)((c.i + 0x7fffu + lsb) >> 16);
}

// ---------------- CSR construction ----------------

__global__ void zero_counts_kernel(int* __restrict__ c1, int* __restrict__ c2) {
    int i = blockIdx.x * 256 + threadIdx.x;
    if (i < NNODES) { c1[i] = 0; c2[i] = 0; }
}

__global__ void hist_kernel(const int* __restrict__ src, const int* __restrict__ dst,
                            int* __restrict__ c1, int* __restrict__ c2) {
    int e = blockIdx.x * 256 + threadIdx.x;
    if (e < NEDGE) {
        atomicAdd(&c1[src[e]], 1);
        atomicAdd(&c2[dst[e]], 1);
    }
}

__global__ __launch_bounds__(1024) void scan_kernel(const int* __restrict__ counts,
                                                    int* __restrict__ rowptr,
                                                    int* __restrict__ cursor) {
    __shared__ int sh[1024];
    int tid = threadIdx.x;
    int base = tid * 8;
    int local[8];
    int sum = 0;
#pragma unroll
    for (int j = 0; j < 8; ++j) { local[j] = counts[base + j]; sum += local[j]; }
    sh[tid] = sum;
    __syncthreads();
    for (int off = 1; off < 1024; off <<= 1) {
        int v = (tid >= off) ? sh[tid - off] : 0;
        __syncthreads();
        sh[tid] += v;
        __syncthreads();
    }
    int p = sh[tid] - sum;
#pragma unroll
    for (int j = 0; j < 8; ++j) {
        cursor[base + j] = p;
        p += local[j];
        rowptr[base + j + 1] = p;
    }
    if (tid == 0) rowptr[0] = 0;
}

__global__ void scatter_kernel(const int* __restrict__ src, const int* __restrict__ dst,
                               const float* __restrict__ v1, const float* __restrict__ v2,
                               int* __restrict__ cur1, int* __restrict__ cur2,
                               int* __restrict__ cols1, float* __restrict__ valsC1,
                               int* __restrict__ cols2, float* __restrict__ valsC2) {
    int e = blockIdx.x * 256 + threadIdx.x;
    if (e < NEDGE) {
        int r1 = src[e];
        int p1 = atomicAdd(&cur1[r1], 1);
        cols1[p1] = dst[e];
        valsC1[p1] = v1[e];
        int r2 = dst[e];
        int p2 = atomicAdd(&cur2[r2], 1);
        cols2[p2] = src[e];
        valsC2[p2] = v2[e];
    }
}

// -------- weight transpose + bf16 convert: W[k=f*5+m][C] -> WT[C][k'=m*72+f] --------

__global__ void convert_w_kernel(const float* __restrict__ Wg, const float* __restrict__ Wc,
                                 ushort* __restrict__ WgT, ushort* __restrict__ WcT) {
    int i = blockIdx.x * 256 + threadIdx.x;
    if (i >= 192 * KP2) return;
    int col = i / KP2, k2 = i - col * KP2;
    int m = k2 / FP2, f = k2 - m * FP2;
    bool valid = (m < 5) && (f < 66);
    int ko = f * 5 + m;
    if (col < 128) {
        WgT[col * KP2 + k2] = valid ? f2bf(Wg[ko * 128 + col]) : (ushort)0;
    } else {
        int c = col - 128;
        WcT[c * KP2 + k2] = valid ? f2bf(Wc[ko * 64 + c]) : (ushort)0;
    }
}

// -------- build x0 (bf16), slice-major: chunk(b>>1, n), half (b&1) --------

__global__ void build_x0_kernel(const float* __restrict__ inputs, const float* __restrict__ state,
                                uint* __restrict__ Xb_u, uint* __restrict__ Xc_u) {
    int t = blockIdx.x * 256 + threadIdx.x;
    if (t >= NNODES * BATCH * 36) return;
    int n = t / 576;           // 576 = 16*36 uints per node
    int r = t - n * 576;       // b*36 + j
    int b = r / 36;
    int j = r - b * 36;
    int f0 = 2 * j;
    uint val = 0;
    if (f0 == 0) {
        float v0 = inputs[(size_t)b * (NNODES * 2) + n * 2 + 0];
        float v1 = inputs[(size_t)b * (NNODES * 2) + n * 2 + 1];
        val = (uint)f2bf(v0) | ((uint)f2bf(v1) << 16);
    } else if (f0 < 66) {
        float v0 = state[(size_t)b * SN + n * HID + (f0 - 2)];
        float v1 = state[(size_t)b * SN + n * HID + (f0 - 1)];
        val = (uint)f2bf(v0) | ((uint)f2bf(v1) << 16);
    }
    // sliced: uint index = ((b>>1)*NNODES + n)*72 + (b&1)*36 + j
    size_t idx = ((size_t)(b >> 1) * NNODES + n) * 72 + (b & 1) * 36 + j;
    Xb_u[idx] = val;                         // slab0 (first slab of Xb)
    if (f0 == 0 || f0 >= 66) Xc_u[idx] = val;  // inputs + zero pads of xc
}

// ---------------- SPMM: slice-major dual-graph gather ----------------
// slice = bid&7 pins each slice to one XCD (round-robin bid->XCD): gathers for
// slice s read only the contiguous 2.36 MB slice region -> L2-resident.
// Writes: node n / n+1 chunks of a slice are memory-adjacent AND same-XCD, so
// L2 assembles full 128 B lines (round-5-clean WRITE). Slice regions are
// 128 B-aligned -> zero cross-XCD line sharing. No NT anywhere.

static __device__ __forceinline__ void fma8(float* acc, uint4 d, float v) {
    acc[0] += v * bf2f((ushort)(d.x));  acc[1] += v * bf2f((ushort)(d.x >> 16));
    acc[2] += v * bf2f((ushort)(d.y));  acc[3] += v * bf2f((ushort)(d.y >> 16));
    acc[4] += v * bf2f((ushort)(d.z));  acc[5] += v * bf2f((ushort)(d.z >> 16));
    acc[6] += v * bf2f((ushort)(d.w));  acc[7] += v * bf2f((ushort)(d.w >> 16));
}

static __device__ __forceinline__ uint4 blend_pack8(const float* acc, uint4 p,
                                                    float alpha, float beta) {
    float o[8];
    o[0] = alpha * acc[0] + beta * bf2f((ushort)(p.x));
    o[1] = alpha * acc[1] + beta * bf2f((ushort)(p.x >> 16));
    o[2] = alpha * acc[2] + beta * bf2f((ushort)(p.y));
    o[3] = alpha * acc[3] + beta * bf2f((ushort)(p.y >> 16));
    o[4] = alpha * acc[4] + beta * bf2f((ushort)(p.z));
    o[5] = alpha * acc[5] + beta * bf2f((ushort)(p.z >> 16));
    o[6] = alpha * acc[6] + beta * bf2f((ushort)(p.w));
    o[7] = alpha * acc[7] + beta * bf2f((ushort)(p.w >> 16));
    uint4 r;
    r.x = (uint32_t)f2bf(o[0]) | ((uint32_t)f2bf(o[1]) << 16);
    r.y = (uint32_t)f2bf(o[2]) | ((uint32_t)f2bf(o[3]) << 16);
    r.z = (uint32_t)f2bf(o[4]) | ((uint32_t)f2bf(o[5]) << 16);
    r.w = (uint32_t)f2bf(o[6]) | ((uint32_t)f2bf(o[7]) << 16);
    return r;
}

__global__ __launch_bounds__(64) void spmm_dual8(
        const int* __restrict__ rp1, const int* __restrict__ c1, const float* __restrict__ v1,
        const uint4* __restrict__ x1,
        const int* __restrict__ rp2, const int* __restrict__ c2, const float* __restrict__ v2,
        const uint4* __restrict__ x2,
        const uint4* __restrict__ xp,
        uint4* __restrict__ y1, uint4* __restrict__ y2,
        float alpha, float beta) {
    int bid = blockIdx.x;
    int slice = bid & 7;            // XCD-pinned slice
    int pair  = bid >> 3;           // graph*8192 + n
    int n     = pair & 8191;
    int graph = pair >> 13;
    const int* rowptr = graph ? rp2 : rp1;
    const int* cols   = graph ? c2 : c1;
    const float* vals = graph ? v2 : v1;
    const uint4* x    = graph ? x2 : x1;
    uint4* y          = graph ? y2 : y1;

    int t = threadIdx.x;
    int eg = t / 18;                // edge group 0..2 (t<54); 3 for idle lanes
    int li = t - eg * 18;           // uint4 index within 18-uint4 chunk
    bool active = t < 54;
    size_t sliceBase = (size_t)slice * NNODES * CHU4;  // slice region base (uint4)
    int s = rowptr[n], e = rowptr[n + 1];
    float acc[8] = {0, 0, 0, 0, 0, 0, 0, 0};
    const uint4 uz = make_uint4(0, 0, 0, 0);
    for (int i = s; i < e; i += 6) {
        int iA = i + eg, iB = i + 3 + eg;
        bool okA = active && (iA < e);
        bool okB = active && (iB < e);
        int cA  = okA ? cols[iA] : 0;
        int cB  = okB ? cols[iB] : 0;
        float vA = okA ? vals[iA] : 0.f;
        float vB = okB ? vals[iB] : 0.f;
        uint4 dA = okA ? x[sliceBase + (size_t)cA * CHU4 + li] : uz;
        uint4 dB = okB ? x[sliceBase + (size_t)cB * CHU4 + li] : uz;
        fma8(acc, dA, vA);
        fma8(acc, dB, vB);
    }
    // reduce 3 edge-groups into lanes 0..17
#pragma unroll
    for (int j = 0; j < 8; ++j) {
        float a18 = __shfl(acc[j], t + 18);
        float a36 = __shfl(acc[j], t + 36);
        acc[j] += a18 + a36;
    }
    if (t < 18) {
        size_t chunk = sliceBase + (size_t)n * CHU4 + t;
        uint4 p = (beta != 0.f) ? xp[chunk] : uz;
        y[chunk] = blend_pack8(acc, p, alpha, beta);
    }
}

// ---------------- gate GEMM: direct-global MFMA fragments, sliced layout ----------------
// Fragment (row=b, f0) lives inside chunk (b>>1, n): off = m*SLABT +
// (b>>1)*SLAB_SL + (b&1)*72 + f0, node term n*144 (uniform). 16 B-aligned.

__global__ __launch_bounds__(256, 2) void gate_mfma(const ushort* __restrict__ Xb,
                                                    const ushort* __restrict__ WgT,
                                                    const float* __restrict__ bg,
                                                    const float* __restrict__ state,
                                                    float* __restrict__ U,
                                                    ushort* __restrict__ Xc) {
    int tid = threadIdx.x;
    int wave = tid >> 6, lane = tid & 63;
    int row = lane & 15, quad = lane >> 4;
    int c0 = wave * 32 + row;
    int c1 = c0 + 16;

    bf16x8 w0[12], w1[12];
#pragma unroll
    for (int kt = 0; kt < 12; ++kt) {
        w0[kt] = *(const bf16x8*)(WgT + (size_t)c0 * KP2 + kt * 32 + quad * 8);
        w1[kt] = *(const bf16x8*)(WgT + (size_t)c1 * KP2 + kt * 32 + quad * 8);
    }
    float bias0 = bg[c0], bias1 = bg[c1];

    int rowOff = (row >> 1) * SLAB_SL + (row & 1) * FP2;
    int offA[11];
#pragma unroll
    for (int kt = 0; kt < 11; ++kt) {
        int j = 4 * kt + quad;
        int m = j / 9;
        int f0 = 8 * (j - 9 * m);
        offA[kt] = m * SLABT + rowOff + f0;
    }
    int off11 = 4 * SLABT + rowOff + 64;  // kt=11, quad 0 only (k' 352..359)

    int nodeBase = blockIdx.x * GN;
    for (int g = 0; g < GN; ++g) {
        int n = nodeBase + g;
        const ushort* An = Xb + (size_t)n * CHUS;
        f32x4 acc0 = {0.f, 0.f, 0.f, 0.f};
        f32x4 acc1 = {0.f, 0.f, 0.f, 0.f};
#pragma unroll
        for (int kt = 0; kt < 11; ++kt) {
            bf16x8 av = *(const bf16x8*)(An + offA[kt]);
            acc0 = __builtin_amdgcn_mfma_f32_16x16x32_bf16(av, w0[kt], acc0, 0, 0, 0);
            acc1 = __builtin_amdgcn_mfma_f32_16x16x32_bf16(av, w1[kt], acc1, 0, 0, 0);
        }
        {
            bf16x8 av = {0, 0, 0, 0, 0, 0, 0, 0};
            if (quad == 0) av = *(const bf16x8*)(An + off11);
            acc0 = __builtin_amdgcn_mfma_f32_16x16x32_bf16(av, w0[11], acc0, 0, 0, 0);
            acc1 = __builtin_amdgcn_mfma_f32_16x16x32_bf16(av, w1[11], acc1, 0, 0, 0);
        }
        // D: col = lane&15 (-> c0/c1), row b = quad*4 + reg
#pragma unroll
        for (int r = 0; r < 4; ++r) {
            int b = quad * 4 + r;
            float v0 = 1.f / (1.f + __expf(-(acc0[r] + bias0)));
            float v1 = 1.f / (1.f + __expf(-(acc1[r] + bias1)));
            if (wave < 2) {  // cols 0..63: r-gate -> xc state part (bf16, sliced Xc)
                float s0 = state[(size_t)b * SN + n * HID + c0];
                float s1 = state[(size_t)b * SN + n * HID + c1];
                size_t cb = ((size_t)(b >> 1) * NNODES + n) * CHUS + (b & 1) * FP2;
                Xc[cb + 2 + c0] = f2bf(v0 * s0);
                Xc[cb + 2 + c1] = f2bf(v1 * s1);
            } else {         // cols 64..127: u-gate (fp32)
                U[(size_t)b * SN + n * HID + (c0 - HID)] = v0;
                U[(size_t)b * SN + n * HID + (c1 - HID)] = v1;
            }
        }
    }
}

// ---------------- candidate GEMM + tanh + GRU update + output ----------------
// NOTE: U aliases out+OUTHALF (scratch in d_out) -> NO __restrict__ on U/out here.

__global__ __launch_bounds__(256, 2) void cand_mfma(const ushort* __restrict__ Xb,
                                                    const ushort* __restrict__ Xc,
                                                    const ushort* __restrict__ WcT,
                                                    const float* __restrict__ bc,
                                                    const float* __restrict__ state,
                                                    const float* U,
                                                    float* out) {
    int tid = threadIdx.x;
    int wave = tid >> 6, lane = tid & 63;
    int row = lane & 15, quad = lane >> 4;
    int c = wave * 16 + row;

    bf16x8 w[12];
#pragma unroll
    for (int kt = 0; kt < 12; ++kt)
        w[kt] = *(const bf16x8*)(WcT + (size_t)c * KP2 + kt * 32 + quad * 8);
    float bias = bc[c];

    int rowOff = (row >> 1) * SLAB_SL + (row & 1) * FP2;
    int offA[11];
#pragma unroll
    for (int kt = 0; kt < 11; ++kt) {
        int j = 4 * kt + quad;
        int m = j / 9;
        int f0 = 8 * (j - 9 * m);
        offA[kt] = m * SLABT + rowOff + f0;  // m==0 entries are also Xc-valid
    }
    int off11 = 4 * SLABT + rowOff + 64;

    int nodeBase = blockIdx.x * GN;
    for (int g = 0; g < GN; ++g) {
        int n = nodeBase + g;
        const ushort* AnB = Xb + (size_t)n * CHUS;
        const ushort* AnC = Xc + (size_t)n * CHUS;
        f32x4 acc = {0.f, 0.f, 0.f, 0.f};
#pragma unroll
        for (int kt = 0; kt < 11; ++kt) {
            // kt 0,1: pure slab0 (Xc). kt 2: quad0 -> Xc, quads 1..3 -> Xb slab1. kt>=3: Xb.
            const ushort* bp = (kt < 2) ? AnC
                             : (kt == 2 ? (quad == 0 ? AnC : AnB) : AnB);
            bf16x8 av = *(const bf16x8*)(bp + offA[kt]);
            acc = __builtin_amdgcn_mfma_f32_16x16x32_bf16(av, w[kt], acc, 0, 0, 0);
        }
        {
            bf16x8 av = {0, 0, 0, 0, 0, 0, 0, 0};
            if (quad == 0) av = *(const bf16x8*)(AnB + off11);
            acc = __builtin_amdgcn_mfma_f32_16x16x32_bf16(av, w[11], acc, 0, 0, 0);
        }
#pragma unroll
        for (int r = 0; r < 4; ++r) {
            int b = quad * 4 + r;
            float pre = acc[r] + bias;
            float cv = 1.f - 2.f / (__expf(2.f * pre) + 1.f);  // tanh
            size_t idx = (size_t)b * SN + n * HID + c;
            float uv = U[idx];       // read BEFORE the aliased write below
            float s = state[idx];
            float ns = uv * s + (1.f - uv) * cv;
            out[idx] = ns;
            out[OUTHALF + idx] = ns; // overwrites U[idx] (same thread, after read)
        }
    }
}

// ---------------- launch ----------------

extern "C" void kernel_launch(void* const* d_in, const int* in_sizes, int n_in,
                              void* d_out, int out_size, void* d_ws, size_t ws_size,
                              hipStream_t stream) {
    const float* inputs = (const float*)d_in[0];
    const float* state  = (const float*)d_in[1];
    const int*   esrc   = (const int*)d_in[2];
    const int*   edst   = (const int*)d_in[3];
    const float* v1     = (const float*)d_in[4];
    const float* v2     = (const float*)d_in[5];
    const float* Wg     = (const float*)d_in[6];
    const float* bg     = (const float*)d_in[7];
    const float* Wc     = (const float*)d_in[8];
    const float* bc     = (const float*)d_in[9];
    float* out = (float*)d_out;

    char* ws = (char*)d_ws;
    size_t off = 0;
    auto alloc = [&](size_t bytes) -> void* {
        void* p = ws + off;
        off += (bytes + 255) & ~(size_t)255;
        return p;
    };
    ushort* Xb     = (ushort*)alloc((size_t)5 * SLABT * 2);   // 94.4 MB, 5 sliced slabs
    ushort* Xc     = (ushort*)alloc((size_t)SLABT * 2);       // 18.9 MB xc slab (sliced)
    ushort* WgT    = (ushort*)alloc((size_t)128 * KP2 * 2);
    ushort* WcT    = (ushort*)alloc((size_t)64 * KP2 * 2);
    int*   counts1 = (int*)alloc(NNODES * 4);
    int*   counts2 = (int*)alloc(NNODES * 4);
    int*   rowptr1 = (int*)alloc((NNODES + 1) * 4);
    int*   rowptr2 = (int*)alloc((NNODES + 1) * 4);
    int*   cursor1 = (int*)alloc(NNODES * 4);
    int*   cursor2 = (int*)alloc(NNODES * 4);
    int*   cols1   = (int*)alloc(NEDGE * 4);
    int*   cols2   = (int*)alloc(NEDGE * 4);
    float* valsC1  = (float*)alloc(NEDGE * 4);
    float* valsC2  = (float*)alloc(NEDGE * 4);

    // U scratch lives in the second output copy (dead until cand epilogue)
    float* U = out + OUTHALF;

    uint4* Xb4 = (uint4*)Xb;
    uint4* Xc4 = (uint4*)Xc;
    auto slab = [&](int m) { return Xb4 + (size_t)m * SLAB4; };

    // CSR build (graph shared by both diff_convs)
    zero_counts_kernel<<<(NNODES + 255) / 256, 256, 0, stream>>>(counts1, counts2);
    hist_kernel<<<(NEDGE + 255) / 256, 256, 0, stream>>>(esrc, edst, counts1, counts2);
    scan_kernel<<<1, 1024, 0, stream>>>(counts1, rowptr1, cursor1);
    scan_kernel<<<1, 1024, 0, stream>>>(counts2, rowptr2, cursor2);
    scatter_kernel<<<(NEDGE + 255) / 256, 256, 0, stream>>>(esrc, edst, v1, v2,
                                                            cursor1, cursor2,
                                                            cols1, valsC1, cols2, valsC2);

    convert_w_kernel<<<(192 * KP2 + 255) / 256, 256, 0, stream>>>(Wg, Wc, WgT, WcT);
    build_x0_kernel<<<(NNODES * BATCH * 36 + 255) / 256, 256, 0, stream>>>(
        inputs, state, (uint*)Xb, (uint*)Xc);

    const int SPG = 2 * NNODES * 8;  // 2 graphs * 8192 nodes * 8 slices

    // diff_conv #1 diffusion
    spmm_dual8<<<SPG, 64, 0, stream>>>(rowptr1, cols1, valsC1, slab(0),
                                       rowptr2, cols2, valsC2, slab(0),
                                       slab(0), slab(1), slab(3), 1.f, 0.f);
    spmm_dual8<<<SPG, 64, 0, stream>>>(rowptr1, cols1, valsC1, slab(1),
                                       rowptr2, cols2, valsC2, slab(3),
                                       slab(0), slab(2), slab(4), 2.f, -1.f);

    // gate GEMM + sigmoid; writes U (in d_out scratch) and xc slab (sliced Xc)
    gate_mfma<<<NNODES / GN, 256, 0, stream>>>(Xb, WgT, bg, state, U, Xc);

    // diff_conv #2 diffusion on xc
    spmm_dual8<<<SPG, 64, 0, stream>>>(rowptr1, cols1, valsC1, Xc4,
                                       rowptr2, cols2, valsC2, Xc4,
                                       Xc4, slab(1), slab(3), 1.f, 0.f);
    spmm_dual8<<<SPG, 64, 0, stream>>>(rowptr1, cols1, valsC1, slab(1),
                                       rowptr2, cols2, valsC2, slab(3),
                                       Xc4, slab(2), slab(4), 2.f, -1.f);

    // candidate GEMM + tanh + GRU update + duplicated output
    cand_mfma<<<NNODES / GN, 256, 0, stream>>>(Xb, Xc, WcT, bc, state, U, out);
}

// Round 10
// 628.964 us; speedup vs baseline: 1.4615x; 1.4615x over previous
//
#include <hip/hip_runtime.h>
#include <cstddef>
#include <cstdint>

#define NNODES 8192
#define BATCH  16
#define HID    64
#define NEDGE  131072
#define SN     524288   // NNODES * HID (per-batch state stride)
#define OUTHALF 8388608 // BATCH * SN
#define FP2    72       // padded per-slab feature dim (66 real + 6 zero); 72 = 9*8
#define SLABU  1152     // ushorts per (node, slab) = 16*72
#define NSTR   5760     // ushorts per node = 5*SLABU
#define NSTR4  720      // uint4 per node in Xb (5760 ushorts / 8 per uint4)
#define XCS4   144      // uint4 per node in Xc (slab0-only buffer, 1152/8)
#define KP2    384      // padded K' = 12 k-tiles of 32 (360 real + 24 zero)
#define GN     4        // nodes per GEMM block (2048 blocks)

typedef __attribute__((ext_vector_type(8))) short bf16x8;
typedef __attribute__((ext_vector_type(4))) float f32x4;
typedef __attribute__((ext_vector_type(4))) uint uint4n;  // native vec for NT builtins

static __device__ __forceinline__ float bf2f(ushort u) {
    union { uint32_t i; float f; } c; c.i = ((uint32_t)u) << 16; return c.f;
}
static __device__ __forceinline__ ushort f2bf(float f) {
    union { float f; uint32_t i; } c; c.f = f;
    uint32_t lsb = (c.i >> 16) & 1;
    return (ushort)((c.i + 0x7fffu + lsb) >> 16);
}

static __device__ __forceinline__ uint4n nt_load4(const uint4* p) {
    return __builtin_nontemporal_load(reinterpret_cast<const uint4n*>(p));
}
static __device__ __forceinline__ void nt_store4(uint4* p, uint4n v) {
    __builtin_nontemporal_store(v, reinterpret_cast<uint4n*>(p));
}

// ---------------- CSR construction ----------------

__global__ void zero_counts_kernel(int* __restrict__ c1, int* __restrict__ c2) {
    int i = blockIdx.x * 256 + threadIdx.x;
    if (i < NNODES) { c1[i] = 0; c2[i] = 0; }
}

__global__ void hist_kernel(const int* __restrict__ src, const int* __restrict__ dst,
                            int* __restrict__ c1, int* __restrict__ c2) {
    int e = blockIdx.x * 256 + threadIdx.x;
    if (e < NEDGE) {
        atomicAdd(&c1[src[e]], 1);
        atomicAdd(&c2[dst[e]], 1);
    }
}

__global__ __launch_bounds__(1024) void scan_kernel(const int* __restrict__ counts,
                                                    int* __restrict__ rowptr,
                                                    int* __restrict__ cursor) {
    __shared__ int sh[1024];
    int tid = threadIdx.x;
    int base = tid * 8;
    int local[8];
    int sum = 0;
#pragma unroll
    for (int j = 0; j < 8; ++j) { local[j] = counts[base + j]; sum += local[j]; }
    sh[tid] = sum;
    __syncthreads();
    for (int off = 1; off < 1024; off <<= 1) {
        int v = (tid >= off) ? sh[tid - off] : 0;
        __syncthreads();
        sh[tid] += v;
        __syncthreads();
    }
    int p = sh[tid] - sum;
#pragma unroll
    for (int j = 0; j < 8; ++j) {
        cursor[base + j] = p;
        p += local[j];
        rowptr[base + j + 1] = p;
    }
    if (tid == 0) rowptr[0] = 0;
}

__global__ void scatter_kernel(const int* __restrict__ src, const int* __restrict__ dst,
                               const float* __restrict__ v1, const float* __restrict__ v2,
                               int* __restrict__ cur1, int* __restrict__ cur2,
                               int* __restrict__ cols1, float* __restrict__ valsC1,
                               int* __restrict__ cols2, float* __restrict__ valsC2) {
    int e = blockIdx.x * 256 + threadIdx.x;
    if (e < NEDGE) {
        int r1 = src[e];
        int p1 = atomicAdd(&cur1[r1], 1);
        cols1[p1] = dst[e];
        valsC1[p1] = v1[e];
        int r2 = dst[e];
        int p2 = atomicAdd(&cur2[r2], 1);
        cols2[p2] = src[e];
        valsC2[p2] = v2[e];
    }
}

// -------- weight transpose + bf16 convert: W[k=f*5+m][C] -> WT[C][k'=m*72+f] --------

__global__ void convert_w_kernel(const float* __restrict__ Wg, const float* __restrict__ Wc,
                                 ushort* __restrict__ WgT, ushort* __restrict__ WcT) {
    int i = blockIdx.x * 256 + threadIdx.x;
    if (i >= 192 * KP2) return;
    int col = i / KP2, k2 = i - col * KP2;
    int m = k2 / FP2, f = k2 - m * FP2;
    bool valid = (m < 5) && (f < 66);
    int ko = f * 5 + m;
    if (col < 128) {
        WgT[col * KP2 + k2] = valid ? f2bf(Wg[ko * 128 + col]) : (ushort)0;
    } else {
        int c = col - 128;
        WcT[c * KP2 + k2] = valid ? f2bf(Wc[ko * 64 + c]) : (ushort)0;
    }
}

// -------- build x0 (bf16): Xb[n][m=0][b][72], and Xc[n][b][72] input/pad parts --------

__global__ void build_x0_kernel(const float* __restrict__ inputs, const float* __restrict__ state,
                                uint* __restrict__ Xb_u, uint* __restrict__ Xc_u) {
    int t = blockIdx.x * 256 + threadIdx.x;
    if (t >= NNODES * BATCH * 36) return;
    int n = t / 576;           // 576 = 16*36 uints per node-slab
    int r = t - n * 576;       // b*36 + j
    int b = r / 36;
    int j = r - b * 36;
    int f0 = 2 * j;
    uint val = 0;
    if (f0 == 0) {
        float v0 = inputs[(size_t)b * (NNODES * 2) + n * 2 + 0];
        float v1 = inputs[(size_t)b * (NNODES * 2) + n * 2 + 1];
        val = (uint)f2bf(v0) | ((uint)f2bf(v1) << 16);
    } else if (f0 < 66) {
        float v0 = state[(size_t)b * SN + n * HID + (f0 - 2)];
        float v1 = state[(size_t)b * SN + n * HID + (f0 - 1)];
        val = (uint)f2bf(v0) | ((uint)f2bf(v1) << 16);
    }
    Xb_u[(size_t)n * 2880 + r] = val;               // slab0 = first 576 uints of node
    if (f0 == 0 || f0 >= 66) Xc_u[t] = val;         // inputs + zero pads of xc slab0
}

// ---------------- SPMM (bf16 rows, fp32 accumulate), 4-wide edge unroll, dual-graph ----------------
// r5 engine (best measured: 6.9 TB/s effective gather) + NT epilogue:
// y-stores and xp-loads are full-line contiguous streams (2 KB/wave) -> NT them
// so the 37.7 MB write + 18.9 MB xp stream stop evicting the gathered source
// rows from L2 (r5's limiter: FETCH 265 MB @ 3.5 TB/s). Gather loads stay cached.

static __device__ __forceinline__ void fma8(float* acc, uint4 d, float v) {
    acc[0] += v * bf2f((ushort)(d.x));  acc[1] += v * bf2f((ushort)(d.x >> 16));
    acc[2] += v * bf2f((ushort)(d.y));  acc[3] += v * bf2f((ushort)(d.y >> 16));
    acc[4] += v * bf2f((ushort)(d.z));  acc[5] += v * bf2f((ushort)(d.z >> 16));
    acc[6] += v * bf2f((ushort)(d.w));  acc[7] += v * bf2f((ushort)(d.w >> 16));
}

static __device__ __forceinline__ uint4n blend_pack8n(const float* acc, uint4n p,
                                                      float alpha, float beta) {
    float o[8];
    o[0] = alpha * acc[0] + beta * bf2f((ushort)(p.x));
    o[1] = alpha * acc[1] + beta * bf2f((ushort)(p.x >> 16));
    o[2] = alpha * acc[2] + beta * bf2f((ushort)(p.y));
    o[3] = alpha * acc[3] + beta * bf2f((ushort)(p.y >> 16));
    o[4] = alpha * acc[4] + beta * bf2f((ushort)(p.z));
    o[5] = alpha * acc[5] + beta * bf2f((ushort)(p.z >> 16));
    o[6] = alpha * acc[6] + beta * bf2f((ushort)(p.w));
    o[7] = alpha * acc[7] + beta * bf2f((ushort)(p.w >> 16));
    uint4n r;
    r.x = (uint32_t)f2bf(o[0]) | ((uint32_t)f2bf(o[1]) << 16);
    r.y = (uint32_t)f2bf(o[2]) | ((uint32_t)f2bf(o[3]) << 16);
    r.z = (uint32_t)f2bf(o[4]) | ((uint32_t)f2bf(o[5]) << 16);
    r.w = (uint32_t)f2bf(o[6]) | ((uint32_t)f2bf(o[7]) << 16);
    return r;
}

// row = 144 uint4 (2304 B) per (node, slab). strides in uint4 units.
// blocks [0,8192): graph 1; [8192,16384): graph 2. Both halves share xp/alpha/beta.
__global__ __launch_bounds__(128) void spmm_dual(
        const int* __restrict__ rp1, const int* __restrict__ c1, const float* __restrict__ v1,
        const uint4* __restrict__ x1,
        const int* __restrict__ rp2, const int* __restrict__ c2, const float* __restrict__ v2,
        const uint4* __restrict__ x2,
        int xs,
        const uint4* __restrict__ xp, int ps,
        uint4* __restrict__ y1, uint4* __restrict__ y2, int ys,
        float alpha, float beta) {
    int bid = blockIdx.x;
    int half = bid >> 13;
    int n = bid & 8191;
    const int* rowptr = half ? rp2 : rp1;
    const int* cols   = half ? c2 : c1;
    const float* vals = half ? v2 : v1;
    const uint4* x    = half ? x2 : x1;
    uint4* y          = half ? y2 : y1;

    int t = threadIdx.x;
    int s = rowptr[n], e = rowptr[n + 1];
    float a0[8] = {0, 0, 0, 0, 0, 0, 0, 0};
    float a1[8] = {0, 0, 0, 0, 0, 0, 0, 0};
    bool tail = t < 16;         // 144 chunks: t and (t<16 ? 128+t)
    int t2 = 128 + t;
    int i = s;
    for (; i + 4 <= e; i += 4) {
        int cA = cols[i], cB = cols[i + 1], cC = cols[i + 2], cD = cols[i + 3];
        float vA = vals[i], vB = vals[i + 1], vC = vals[i + 2], vD = vals[i + 3];
        const uint4* rA = x + (size_t)cA * xs;
        const uint4* rB = x + (size_t)cB * xs;
        const uint4* rC = x + (size_t)cC * xs;
        const uint4* rD = x + (size_t)cD * xs;
        uint4 dA = rA[t], dB = rB[t], dC = rC[t], dD = rD[t];
        uint4 eA, eB, eC, eD;
        if (tail) { eA = rA[t2]; eB = rB[t2]; eC = rC[t2]; eD = rD[t2]; }
        fma8(a0, dA, vA); fma8(a0, dB, vB); fma8(a0, dC, vC); fma8(a0, dD, vD);
        if (tail) { fma8(a1, eA, vA); fma8(a1, eB, vB); fma8(a1, eC, vC); fma8(a1, eD, vD); }
    }
    for (; i < e; ++i) {
        int cA = cols[i];
        float vA = vals[i];
        const uint4* rA = x + (size_t)cA * xs;
        uint4 dA = rA[t];
        if (tail) { uint4 dA1 = rA[t2]; fma8(a1, dA1, vA); }
        fma8(a0, dA, vA);
    }
    uint4* yb = y + (size_t)n * ys;
    const uint4* xpb = xp + (size_t)n * ps;
    uint4n p0 = {0, 0, 0, 0};
    if (beta != 0.f) p0 = nt_load4(xpb + t);
    nt_store4(yb + t, blend_pack8n(a0, p0, alpha, beta));
    if (tail) {
        uint4n p1 = {0, 0, 0, 0};
        if (beta != 0.f) p1 = nt_load4(xpb + t2);
        nt_store4(yb + t2, blend_pack8n(a1, p1, alpha, beta));
    }
}

// ---------------- gate GEMM: direct-global MFMA fragments, no LDS, no barriers ----------------

__global__ __launch_bounds__(256, 2) void gate_mfma(const ushort* __restrict__ Xb,
                                                    const ushort* __restrict__ WgT,
                                                    const float* __restrict__ bg,
                                                    const float* __restrict__ state,
                                                    float* __restrict__ U,
                                                    ushort* __restrict__ Xc) {
    int tid = threadIdx.x;
    int wave = tid >> 6, lane = tid & 63;
    int row = lane & 15, quad = lane >> 4;
    int c0 = wave * 32 + row;
    int c1 = c0 + 16;

    bf16x8 w0[12], w1[12];
#pragma unroll
    for (int kt = 0; kt < 12; ++kt) {
        w0[kt] = *(const bf16x8*)(WgT + (size_t)c0 * KP2 + kt * 32 + quad * 8);
        w1[kt] = *(const bf16x8*)(WgT + (size_t)c1 * KP2 + kt * 32 + quad * 8);
    }
    float bias0 = bg[c0], bias1 = bg[c1];

    // per-lane A-fragment offsets (ushort units): k' = 8*(4*kt+quad) = m*72+f0
    int offA[11];
#pragma unroll
    for (int kt = 0; kt < 11; ++kt) {
        int j = 4 * kt + quad;
        int m = j / 9;
        int f0 = 8 * (j - 9 * m);
        offA[kt] = m * SLABU + row * FP2 + f0;
    }
    int off11 = 4 * SLABU + row * FP2 + 64;  // kt=11, quad 0 only (k' 352..359)

    int nodeBase = blockIdx.x * GN;
    for (int g = 0; g < GN; ++g) {
        int n = nodeBase + g;
        const ushort* An = Xb + (size_t)n * NSTR;
        f32x4 acc0 = {0.f, 0.f, 0.f, 0.f};
        f32x4 acc1 = {0.f, 0.f, 0.f, 0.f};
#pragma unroll
        for (int kt = 0; kt < 11; ++kt) {
            bf16x8 av = *(const bf16x8*)(An + offA[kt]);
            acc0 = __builtin_amdgcn_mfma_f32_16x16x32_bf16(av, w0[kt], acc0, 0, 0, 0);
            acc1 = __builtin_amdgcn_mfma_f32_16x16x32_bf16(av, w1[kt], acc1, 0, 0, 0);
        }
        {
            bf16x8 av = {0, 0, 0, 0, 0, 0, 0, 0};
            if (quad == 0) av = *(const bf16x8*)(An + off11);
            acc0 = __builtin_amdgcn_mfma_f32_16x16x32_bf16(av, w0[11], acc0, 0, 0, 0);
            acc1 = __builtin_amdgcn_mfma_f32_16x16x32_bf16(av, w1[11], acc1, 0, 0, 0);
        }
        // D: col = lane&15 (-> c0/c1), row b = quad*4 + reg
#pragma unroll
        for (int r = 0; r < 4; ++r) {
            int b = quad * 4 + r;
            float v0 = 1.f / (1.f + __expf(-(acc0[r] + bias0)));
            float v1 = 1.f / (1.f + __expf(-(acc1[r] + bias1)));
            if (wave < 2) {  // cols 0..63: r-gate -> xc state part (bf16, separate buffer)
                float s0 = state[(size_t)b * SN + n * HID + c0];
                float s1 = state[(size_t)b * SN + n * HID + c1];
                Xc[(size_t)n * SLABU + b * FP2 + 2 + c0] = f2bf(v0 * s0);
                Xc[(size_t)n * SLABU + b * FP2 + 2 + c1] = f2bf(v1 * s1);
            } else {         // cols 64..127: u-gate (fp32)
                U[(size_t)b * SN + n * HID + (c0 - HID)] = v0;
                U[(size_t)b * SN + n * HID + (c1 - HID)] = v1;
            }
        }
    }
}

// ---------------- candidate GEMM + tanh + GRU update + output ----------------
// NOTE: U aliases out+OUTHALF (scratch in d_out) -> NO __restrict__ on U/out here.

__global__ __launch_bounds__(256, 2) void cand_mfma(const ushort* __restrict__ Xb,
                                                    const ushort* __restrict__ Xc,
                                                    const ushort* __restrict__ WcT,
                                                    const float* __restrict__ bc,
                                                    const float* __restrict__ state,
                                                    const float* U,
                                                    float* out) {
    int tid = threadIdx.x;
    int wave = tid >> 6, lane = tid & 63;
    int row = lane & 15, quad = lane >> 4;
    int c = wave * 16 + row;

    bf16x8 w[12];
#pragma unroll
    for (int kt = 0; kt < 12; ++kt)
        w[kt] = *(const bf16x8*)(WcT + (size_t)c * KP2 + kt * 32 + quad * 8);
    float bias = bc[c];

    int offA[11];
#pragma unroll
    for (int kt = 0; kt < 11; ++kt) {
        int j = 4 * kt + quad;
        int m = j / 9;
        int f0 = 8 * (j - 9 * m);
        offA[kt] = m * SLABU + row * FP2 + f0;  // m==0 offsets are also Xc-relative
    }
    int off11 = 4 * SLABU + row * FP2 + 64;

    int nodeBase = blockIdx.x * GN;
    for (int g = 0; g < GN; ++g) {
        int n = nodeBase + g;
        const ushort* AnB = Xb + (size_t)n * NSTR;
        const ushort* AnC = Xc + (size_t)n * SLABU;
        f32x4 acc = {0.f, 0.f, 0.f, 0.f};
#pragma unroll
        for (int kt = 0; kt < 11; ++kt) {
            // kt 0,1: pure slab0 (Xc). kt 2: quad0 -> Xc, quads 1..3 -> Xb slab1. kt>=3: Xb.
            const ushort* bp = (kt < 2) ? AnC
                             : (kt == 2 ? (quad == 0 ? AnC : AnB) : AnB);
            bf16x8 av = *(const bf16x8*)(bp + offA[kt]);
            acc = __builtin_amdgcn_mfma_f32_16x16x32_bf16(av, w[kt], acc, 0, 0, 0);
        }
        {
            bf16x8 av = {0, 0, 0, 0, 0, 0, 0, 0};
            if (quad == 0) av = *(const bf16x8*)(AnB + off11);
            acc = __builtin_amdgcn_mfma_f32_16x16x32_bf16(av, w[11], acc, 0, 0, 0);
        }
#pragma unroll
        for (int r = 0; r < 4; ++r) {
            int b = quad * 4 + r;
            float pre = acc[r] + bias;
            float cv = 1.f - 2.f / (__expf(2.f * pre) + 1.f);  // tanh
            size_t idx = (size_t)b * SN + n * HID + c;
            float uv = U[idx];       // read BEFORE the aliased write below
            float s = state[idx];
            float ns = uv * s + (1.f - uv) * cv;
            out[idx] = ns;
            out[OUTHALF + idx] = ns; // overwrites U[idx] (same thread, after read)
        }
    }
}

// ---------------- launch ----------------

extern "C" void kernel_launch(void* const* d_in, const int* in_sizes, int n_in,
                              void* d_out, int out_size, void* d_ws, size_t ws_size,
                              hipStream_t stream) {
    const float* inputs = (const float*)d_in[0];
    const float* state  = (const float*)d_in[1];
    const int*   esrc   = (const int*)d_in[2];
    const int*   edst   = (const int*)d_in[3];
    const float* v1     = (const float*)d_in[4];
    const float* v2     = (const float*)d_in[5];
    const float* Wg     = (const float*)d_in[6];
    const float* bg     = (const float*)d_in[7];
    const float* Wc     = (const float*)d_in[8];
    const float* bc     = (const float*)d_in[9];
    float* out = (float*)d_out;

    char* ws = (char*)d_ws;
    size_t off = 0;
    auto alloc = [&](size_t bytes) -> void* {
        void* p = ws + off;
        off += (bytes + 255) & ~(size_t)255;
        return p;
    };
    ushort* Xb     = (ushort*)alloc((size_t)NNODES * NSTR * 2);   // 94.4 MB [n][m][b][72]
    ushort* Xc     = (ushort*)alloc((size_t)NNODES * SLABU * 2);  // 18.9 MB xc slab0
    ushort* WgT    = (ushort*)alloc((size_t)128 * KP2 * 2);
    ushort* WcT    = (ushort*)alloc((size_t)64 * KP2 * 2);
    int*   counts1 = (int*)alloc(NNODES * 4);
    int*   counts2 = (int*)alloc(NNODES * 4);
    int*   rowptr1 = (int*)alloc((NNODES + 1) * 4);
    int*   rowptr2 = (int*)alloc((NNODES + 1) * 4);
    int*   cursor1 = (int*)alloc(NNODES * 4);
    int*   cursor2 = (int*)alloc(NNODES * 4);
    int*   cols1   = (int*)alloc(NEDGE * 4);
    int*   cols2   = (int*)alloc(NEDGE * 4);
    float* valsC1  = (float*)alloc(NEDGE * 4);
    float* valsC2  = (float*)alloc(NEDGE * 4);

    // U scratch lives in the second output copy (dead until cand epilogue)
    float* U = out + OUTHALF;

    uint4* Xb4 = (uint4*)Xb;
    uint4* Xc4 = (uint4*)Xc;
    auto slab = [&](int m) { return Xb4 + (size_t)m * 144; };  // slab m base, node stride 720

    // CSR build (graph shared by both diff_convs)
    zero_counts_kernel<<<(NNODES + 255) / 256, 256, 0, stream>>>(counts1, counts2);
    hist_kernel<<<(NEDGE + 255) / 256, 256, 0, stream>>>(esrc, edst, counts1, counts2);
    scan_kernel<<<1, 1024, 0, stream>>>(counts1, rowptr1, cursor1);
    scan_kernel<<<1, 1024, 0, stream>>>(counts2, rowptr2, cursor2);
    scatter_kernel<<<(NEDGE + 255) / 256, 256, 0, stream>>>(esrc, edst, v1, v2,
                                                            cursor1, cursor2,
                                                            cols1, valsC1, cols2, valsC2);

    convert_w_kernel<<<(192 * KP2 + 255) / 256, 256, 0, stream>>>(Wg, Wc, WgT, WcT);
    build_x0_kernel<<<(NNODES * BATCH * 36 + 255) / 256, 256, 0, stream>>>(
        inputs, state, (uint*)Xb, (uint*)Xc);

    // diff_conv #1 diffusion: both graphs per dispatch (dual)
    spmm_dual<<<2 * NNODES, 128, 0, stream>>>(rowptr1, cols1, valsC1, slab(0),
                                              rowptr2, cols2, valsC2, slab(0), NSTR4,
                                              slab(0), NSTR4, slab(1), slab(3), NSTR4,
                                              1.f, 0.f);
    spmm_dual<<<2 * NNODES, 128, 0, stream>>>(rowptr1, cols1, valsC1, slab(1),
                                              rowptr2, cols2, valsC2, slab(3), NSTR4,
                                              slab(0), NSTR4, slab(2), slab(4), NSTR4,
                                              2.f, -1.f);

    // gate GEMM + sigmoid; writes U (in d_out scratch) and xc slab0 (r*state) into Xc
    gate_mfma<<<NNODES / GN, 256, 0, stream>>>(Xb, WgT, bg, state, U, Xc);

    // diff_conv #2 diffusion on xc (x0 := Xc, node stride 144 uint4)
    spmm_dual<<<2 * NNODES, 128, 0, stream>>>(rowptr1, cols1, valsC1, Xc4,
                                              rowptr2, cols2, valsC2, Xc4, XCS4,
                                              Xc4, XCS4, slab(1), slab(3), NSTR4,
                                              1.f, 0.f);
    spmm_dual<<<2 * NNODES, 128, 0, stream>>>(rowptr1, cols1, valsC1, slab(1),
                                              rowptr2, cols2, valsC2, slab(3), NSTR4,
                                              Xc4, XCS4, slab(2), slab(4), NSTR4,
                                              2.f, -1.f);

    // candidate GEMM + tanh + GRU update + duplicated output
    cand_mfma<<<NNODES / GN, 256, 0, stream>>>(Xb, Xc, WcT, bc, state, U, out);
}

// Round 11
// 586.764 us; speedup vs baseline: 1.5666x; 1.0719x over previous
//
#include <hip/hip_runtime.h>
#include <cstddef>
#include <cstdint>

#define NNODES 8192
#define BATCH  16
#define HID    64
#define NEDGE  131072
#define SN     524288   // NNODES * HID (per-batch state stride)
#define OUTHALF 8388608 // BATCH * SN
#define FP2    72       // padded per-slab feature dim (66 real + 6 zero); 72 = 9*8
#define SLABU  1152     // ushorts per (node, slab) = 16*72
#define NSTR   5760     // ushorts per node = 5*SLABU
#define NSTR4  720      // uint4 per node in Xb (5760 ushorts / 8 per uint4)
#define XCS4   144      // uint4 per node in Xc (slab0-only buffer, 1152/8)
#define KP2    384      // padded K' = 12 k-tiles of 32 (360 real + 24 zero)
#define GN     8        // nodes per GEMM block (1024 blocks; r4-measured best)

typedef __attribute__((ext_vector_type(8))) short bf16x8;
typedef __attribute__((ext_vector_type(4))) float f32x4;

static __device__ __forceinline__ float bf2f(ushort u) {
    union { uint32_t i; float f; } c; c.i = ((uint32_t)u) << 16; return c.f;
}
static __device__ __forceinline__ ushort f2bf(float f) {
    union { float f; uint32_t i; } c; c.f = f;
    uint32_t lsb = (c.i >> 16) & 1;
    return (ushort)((c.i + 0x7fffu + lsb) >> 16);
}

// ---------------- CSR construction ----------------

__global__ void zero_counts_kernel(int* __restrict__ c1, int* __restrict__ c2) {
    int i = blockIdx.x * 256 + threadIdx.x;
    if (i < NNODES) { c1[i] = 0; c2[i] = 0; }
}

__global__ void hist_kernel(const int* __restrict__ src, const int* __restrict__ dst,
                            int* __restrict__ c1, int* __restrict__ c2) {
    int e = blockIdx.x * 256 + threadIdx.x;
    if (e < NEDGE) {
        atomicAdd(&c1[src[e]], 1);
        atomicAdd(&c2[dst[e]], 1);
    }
}

__global__ __launch_bounds__(1024) void scan_kernel(const int* __restrict__ counts,
                                                    int* __restrict__ rowptr,
                                                    int* __restrict__ cursor) {
    __shared__ int sh[1024];
    int tid = threadIdx.x;
    int base = tid * 8;
    int local[8];
    int sum = 0;
#pragma unroll
    for (int j = 0; j < 8; ++j) { local[j] = counts[base + j]; sum += local[j]; }
    sh[tid] = sum;
    __syncthreads();
    for (int off = 1; off < 1024; off <<= 1) {
        int v = (tid >= off) ? sh[tid - off] : 0;
        __syncthreads();
        sh[tid] += v;
        __syncthreads();
    }
    int p = sh[tid] - sum;
#pragma unroll
    for (int j = 0; j < 8; ++j) {
        cursor[base + j] = p;
        p += local[j];
        rowptr[base + j + 1] = p;
    }
    if (tid == 0) rowptr[0] = 0;
}

__global__ void scatter_kernel(const int* __restrict__ src, const int* __restrict__ dst,
                               const float* __restrict__ v1, const float* __restrict__ v2,
                               int* __restrict__ cur1, int* __restrict__ cur2,
                               int* __restrict__ cols1, float* __restrict__ valsC1,
                               int* __restrict__ cols2, float* __restrict__ valsC2) {
    int e = blockIdx.x * 256 + threadIdx.x;
    if (e < NEDGE) {
        int r1 = src[e];
        int p1 = atomicAdd(&cur1[r1], 1);
        cols1[p1] = dst[e];
        valsC1[p1] = v1[e];
        int r2 = dst[e];
        int p2 = atomicAdd(&cur2[r2], 1);
        cols2[p2] = src[e];
        valsC2[p2] = v2[e];
    }
}

// -------- weight transpose + bf16 convert: W[k=f*5+m][C] -> WT[C][k'=m*72+f] --------

__global__ void convert_w_kernel(const float* __restrict__ Wg, const float* __restrict__ Wc,
                                 ushort* __restrict__ WgT, ushort* __restrict__ WcT) {
    int i = blockIdx.x * 256 + threadIdx.x;
    if (i >= 192 * KP2) return;
    int col = i / KP2, k2 = i - col * KP2;
    int m = k2 / FP2, f = k2 - m * FP2;
    bool valid = (m < 5) && (f < 66);
    int ko = f * 5 + m;
    if (col < 128) {
        WgT[col * KP2 + k2] = valid ? f2bf(Wg[ko * 128 + col]) : (ushort)0;
    } else {
        int c = col - 128;
        WcT[c * KP2 + k2] = valid ? f2bf(Wc[ko * 64 + c]) : (ushort)0;
    }
}

// -------- build x0 (bf16): Xb[n][m=0][b][72], and Xc[n][b][72] input/pad parts --------

__global__ void build_x0_kernel(const float* __restrict__ inputs, const float* __restrict__ state,
                                uint* __restrict__ Xb_u, uint* __restrict__ Xc_u) {
    int t = blockIdx.x * 256 + threadIdx.x;
    if (t >= NNODES * BATCH * 36) return;
    int n = t / 576;           // 576 = 16*36 uints per node-slab
    int r = t - n * 576;       // b*36 + j
    int b = r / 36;
    int j = r - b * 36;
    int f0 = 2 * j;
    uint val = 0;
    if (f0 == 0) {
        float v0 = inputs[(size_t)b * (NNODES * 2) + n * 2 + 0];
        float v1 = inputs[(size_t)b * (NNODES * 2) + n * 2 + 1];
        val = (uint)f2bf(v0) | ((uint)f2bf(v1) << 16);
    } else if (f0 < 66) {
        float v0 = state[(size_t)b * SN + n * HID + (f0 - 2)];
        float v1 = state[(size_t)b * SN + n * HID + (f0 - 1)];
        val = (uint)f2bf(v0) | ((uint)f2bf(v1) << 16);
    }
    Xb_u[(size_t)n * 2880 + r] = val;               // slab0 = first 576 uints of node
    if (f0 == 0 || f0 >= 66) Xc_u[t] = val;         // inputs + zero pads of xc slab0
}

// ---------------- SPMM (bf16 rows, fp32 accumulate), 4-wide edge unroll, dual-graph ----------------
// r5 engine exactly (best measured: 87 us/dispatch, 6.9 TB/s effective gather).
// Normal (cached) stores: the produced slabs stay in L2 for the downstream
// GEMMs -- NT here cost gate_mfma +26 us in r10 (producer->consumer reuse).

static __device__ __forceinline__ void fma8(float* acc, uint4 d, float v) {
    acc[0] += v * bf2f((ushort)(d.x));  acc[1] += v * bf2f((ushort)(d.x >> 16));
    acc[2] += v * bf2f((ushort)(d.y));  acc[3] += v * bf2f((ushort)(d.y >> 16));
    acc[4] += v * bf2f((ushort)(d.z));  acc[5] += v * bf2f((ushort)(d.z >> 16));
    acc[6] += v * bf2f((ushort)(d.w));  acc[7] += v * bf2f((ushort)(d.w >> 16));
}

static __device__ __forceinline__ uint4 blend_pack8(const float* acc, uint4 p,
                                                    float alpha, float beta) {
    float o[8];
    o[0] = alpha * acc[0] + beta * bf2f((ushort)(p.x));
    o[1] = alpha * acc[1] + beta * bf2f((ushort)(p.x >> 16));
    o[2] = alpha * acc[2] + beta * bf2f((ushort)(p.y));
    o[3] = alpha * acc[3] + beta * bf2f((ushort)(p.y >> 16));
    o[4] = alpha * acc[4] + beta * bf2f((ushort)(p.z));
    o[5] = alpha * acc[5] + beta * bf2f((ushort)(p.z >> 16));
    o[6] = alpha * acc[6] + beta * bf2f((ushort)(p.w));
    o[7] = alpha * acc[7] + beta * bf2f((ushort)(p.w >> 16));
    uint4 r;
    r.x = (uint32_t)f2bf(o[0]) | ((uint32_t)f2bf(o[1]) << 16);
    r.y = (uint32_t)f2bf(o[2]) | ((uint32_t)f2bf(o[3]) << 16);
    r.z = (uint32_t)f2bf(o[4]) | ((uint32_t)f2bf(o[5]) << 16);
    r.w = (uint32_t)f2bf(o[6]) | ((uint32_t)f2bf(o[7]) << 16);
    return r;
}

// row = 144 uint4 (2304 B) per (node, slab). strides in uint4 units.
// blocks [0,8192): graph 1; [8192,16384): graph 2. Both halves share xp/alpha/beta.
__global__ __launch_bounds__(128) void spmm_dual(
        const int* __restrict__ rp1, const int* __restrict__ c1, const float* __restrict__ v1,
        const uint4* __restrict__ x1,
        const int* __restrict__ rp2, const int* __restrict__ c2, const float* __restrict__ v2,
        const uint4* __restrict__ x2,
        int xs,
        const uint4* __restrict__ xp, int ps,
        uint4* __restrict__ y1, uint4* __restrict__ y2, int ys,
        float alpha, float beta) {
    int bid = blockIdx.x;
    int half = bid >> 13;
    int n = bid & 8191;
    const int* rowptr = half ? rp2 : rp1;
    const int* cols   = half ? c2 : c1;
    const float* vals = half ? v2 : v1;
    const uint4* x    = half ? x2 : x1;
    uint4* y          = half ? y2 : y1;

    int t = threadIdx.x;
    int s = rowptr[n], e = rowptr[n + 1];
    float a0[8] = {0, 0, 0, 0, 0, 0, 0, 0};
    float a1[8] = {0, 0, 0, 0, 0, 0, 0, 0};
    bool tail = t < 16;         // 144 chunks: t and (t<16 ? 128+t)
    int t2 = 128 + t;
    int i = s;
    for (; i + 4 <= e; i += 4) {
        int cA = cols[i], cB = cols[i + 1], cC = cols[i + 2], cD = cols[i + 3];
        float vA = vals[i], vB = vals[i + 1], vC = vals[i + 2], vD = vals[i + 3];
        const uint4* rA = x + (size_t)cA * xs;
        const uint4* rB = x + (size_t)cB * xs;
        const uint4* rC = x + (size_t)cC * xs;
        const uint4* rD = x + (size_t)cD * xs;
        uint4 dA = rA[t], dB = rB[t], dC = rC[t], dD = rD[t];
        uint4 eA, eB, eC, eD;
        if (tail) { eA = rA[t2]; eB = rB[t2]; eC = rC[t2]; eD = rD[t2]; }
        fma8(a0, dA, vA); fma8(a0, dB, vB); fma8(a0, dC, vC); fma8(a0, dD, vD);
        if (tail) { fma8(a1, eA, vA); fma8(a1, eB, vB); fma8(a1, eC, vC); fma8(a1, eD, vD); }
    }
    for (; i < e; ++i) {
        int cA = cols[i];
        float vA = vals[i];
        const uint4* rA = x + (size_t)cA * xs;
        uint4 dA = rA[t];
        if (tail) { uint4 dA1 = rA[t2]; fma8(a1, dA1, vA); }
        fma8(a0, dA, vA);
    }
    uint4* yb = y + (size_t)n * ys;
    const uint4* xpb = xp + (size_t)n * ps;
    uint4 p0 = (beta != 0.f) ? xpb[t] : make_uint4(0, 0, 0, 0);
    yb[t] = blend_pack8(a0, p0, alpha, beta);
    if (tail) {
        uint4 p1 = (beta != 0.f) ? xpb[t2] : make_uint4(0, 0, 0, 0);
        yb[t2] = blend_pack8(a1, p1, alpha, beta);
    }
}

// ---------------- gate GEMM: direct-global MFMA fragments, no LDS, no barriers ----------------
// r4 config exactly (measured 71 us): GN=8, (256,2), VGPR 76, no spill.

__global__ __launch_bounds__(256, 2) void gate_mfma(const ushort* __restrict__ Xb,
                                                    const ushort* __restrict__ WgT,
                                                    const float* __restrict__ bg,
                                                    const float* __restrict__ state,
                                                    float* __restrict__ U,
                                                    ushort* __restrict__ Xc) {
    int tid = threadIdx.x;
    int wave = tid >> 6, lane = tid & 63;
    int row = lane & 15, quad = lane >> 4;
    int c0 = wave * 32 + row;
    int c1 = c0 + 16;

    bf16x8 w0[12], w1[12];
#pragma unroll
    for (int kt = 0; kt < 12; ++kt) {
        w0[kt] = *(const bf16x8*)(WgT + (size_t)c0 * KP2 + kt * 32 + quad * 8);
        w1[kt] = *(const bf16x8*)(WgT + (size_t)c1 * KP2 + kt * 32 + quad * 8);
    }
    float bias0 = bg[c0], bias1 = bg[c1];

    // per-lane A-fragment offsets (ushort units): k' = 8*(4*kt+quad) = m*72+f0
    int offA[11];
#pragma unroll
    for (int kt = 0; kt < 11; ++kt) {
        int j = 4 * kt + quad;
        int m = j / 9;
        int f0 = 8 * (j - 9 * m);
        offA[kt] = m * SLABU + row * FP2 + f0;
    }
    int off11 = 4 * SLABU + row * FP2 + 64;  // kt=11, quad 0 only (k' 352..359)

    int nodeBase = blockIdx.x * GN;
    for (int g = 0; g < GN; ++g) {
        int n = nodeBase + g;
        const ushort* An = Xb + (size_t)n * NSTR;
        f32x4 acc0 = {0.f, 0.f, 0.f, 0.f};
        f32x4 acc1 = {0.f, 0.f, 0.f, 0.f};
#pragma unroll
        for (int kt = 0; kt < 11; ++kt) {
            bf16x8 av = *(const bf16x8*)(An + offA[kt]);
            acc0 = __builtin_amdgcn_mfma_f32_16x16x32_bf16(av, w0[kt], acc0, 0, 0, 0);
            acc1 = __builtin_amdgcn_mfma_f32_16x16x32_bf16(av, w1[kt], acc1, 0, 0, 0);
        }
        {
            bf16x8 av = {0, 0, 0, 0, 0, 0, 0, 0};
            if (quad == 0) av = *(const bf16x8*)(An + off11);
            acc0 = __builtin_amdgcn_mfma_f32_16x16x32_bf16(av, w0[11], acc0, 0, 0, 0);
            acc1 = __builtin_amdgcn_mfma_f32_16x16x32_bf16(av, w1[11], acc1, 0, 0, 0);
        }
        // D: col = lane&15 (-> c0/c1), row b = quad*4 + reg
#pragma unroll
        for (int r = 0; r < 4; ++r) {
            int b = quad * 4 + r;
            float v0 = 1.f / (1.f + __expf(-(acc0[r] + bias0)));
            float v1 = 1.f / (1.f + __expf(-(acc1[r] + bias1)));
            if (wave < 2) {  // cols 0..63: r-gate -> xc state part (bf16, separate buffer)
                float s0 = state[(size_t)b * SN + n * HID + c0];
                float s1 = state[(size_t)b * SN + n * HID + c1];
                Xc[(size_t)n * SLABU + b * FP2 + 2 + c0] = f2bf(v0 * s0);
                Xc[(size_t)n * SLABU + b * FP2 + 2 + c1] = f2bf(v1 * s1);
            } else {         // cols 64..127: u-gate (fp32)
                U[(size_t)b * SN + n * HID + (c0 - HID)] = v0;
                U[(size_t)b * SN + n * HID + (c1 - HID)] = v1;
            }
        }
    }
}

// ---------------- candidate GEMM + tanh + GRU update + output ----------------
// NOTE: U aliases out+OUTHALF (scratch in d_out) -> NO __restrict__ on U/out here.

__global__ __launch_bounds__(256, 3) void cand_mfma(const ushort* __restrict__ Xb,
                                                    const ushort* __restrict__ Xc,
                                                    const ushort* __restrict__ WcT,
                                                    const float* __restrict__ bc,
                                                    const float* __restrict__ state,
                                                    const float* U,
                                                    float* out) {
    int tid = threadIdx.x;
    int wave = tid >> 6, lane = tid & 63;
    int row = lane & 15, quad = lane >> 4;
    int c = wave * 16 + row;

    bf16x8 w[12];
#pragma unroll
    for (int kt = 0; kt < 12; ++kt)
        w[kt] = *(const bf16x8*)(WcT + (size_t)c * KP2 + kt * 32 + quad * 8);
    float bias = bc[c];

    int offA[11];
#pragma unroll
    for (int kt = 0; kt < 11; ++kt) {
        int j = 4 * kt + quad;
        int m = j / 9;
        int f0 = 8 * (j - 9 * m);
        offA[kt] = m * SLABU + row * FP2 + f0;  // m==0 offsets are also Xc-relative
    }
    int off11 = 4 * SLABU + row * FP2 + 64;

    int nodeBase = blockIdx.x * GN;
    for (int g = 0; g < GN; ++g) {
        int n = nodeBase + g;
        const ushort* AnB = Xb + (size_t)n * NSTR;
        const ushort* AnC = Xc + (size_t)n * SLABU;
        f32x4 acc = {0.f, 0.f, 0.f, 0.f};
#pragma unroll
        for (int kt = 0; kt < 11; ++kt) {
            // kt 0,1: pure slab0 (Xc). kt 2: quad0 -> Xc, quads 1..3 -> Xb slab1. kt>=3: Xb.
            const ushort* bp = (kt < 2) ? AnC
                             : (kt == 2 ? (quad == 0 ? AnC : AnB) : AnB);
            bf16x8 av = *(const bf16x8*)(bp + offA[kt]);
            acc = __builtin_amdgcn_mfma_f32_16x16x32_bf16(av, w[kt], acc, 0, 0, 0);
        }
        {
            bf16x8 av = {0, 0, 0, 0, 0, 0, 0, 0};
            if (quad == 0) av = *(const bf16x8*)(AnB + off11);
            acc = __builtin_amdgcn_mfma_f32_16x16x32_bf16(av, w[11], acc, 0, 0, 0);
        }
#pragma unroll
        for (int r = 0; r < 4; ++r) {
            int b = quad * 4 + r;
            float pre = acc[r] + bias;
            float cv = 1.f - 2.f / (__expf(2.f * pre) + 1.f);  // tanh
            size_t idx = (size_t)b * SN + n * HID + c;
            float uv = U[idx];       // read BEFORE the aliased write below
            float s = state[idx];
            float ns = uv * s + (1.f - uv) * cv;
            out[idx] = ns;
            out[OUTHALF + idx] = ns; // overwrites U[idx] (same thread, after read)
        }
    }
}

// ---------------- launch ----------------

extern "C" void kernel_launch(void* const* d_in, const int* in_sizes, int n_in,
                              void* d_out, int out_size, void* d_ws, size_t ws_size,
                              hipStream_t stream) {
    const float* inputs = (const float*)d_in[0];
    const float* state  = (const float*)d_in[1];
    const int*   esrc   = (const int*)d_in[2];
    const int*   edst   = (const int*)d_in[3];
    const float* v1     = (const float*)d_in[4];
    const float* v2     = (const float*)d_in[5];
    const float* Wg     = (const float*)d_in[6];
    const float* bg     = (const float*)d_in[7];
    const float* Wc     = (const float*)d_in[8];
    const float* bc     = (const float*)d_in[9];
    float* out = (float*)d_out;

    char* ws = (char*)d_ws;
    size_t off = 0;
    auto alloc = [&](size_t bytes) -> void* {
        void* p = ws + off;
        off += (bytes + 255) & ~(size_t)255;
        return p;
    };
    ushort* Xb     = (ushort*)alloc((size_t)NNODES * NSTR * 2);   // 94.4 MB [n][m][b][72]
    ushort* Xc     = (ushort*)alloc((size_t)NNODES * SLABU * 2);  // 18.9 MB xc slab0
    ushort* WgT    = (ushort*)alloc((size_t)128 * KP2 * 2);
    ushort* WcT    = (ushort*)alloc((size_t)64 * KP2 * 2);
    int*   counts1 = (int*)alloc(NNODES * 4);
    int*   counts2 = (int*)alloc(NNODES * 4);
    int*   rowptr1 = (int*)alloc((NNODES + 1) * 4);
    int*   rowptr2 = (int*)alloc((NNODES + 1) * 4);
    int*   cursor1 = (int*)alloc(NNODES * 4);
    int*   cursor2 = (int*)alloc(NNODES * 4);
    int*   cols1   = (int*)alloc(NEDGE * 4);
    int*   cols2   = (int*)alloc(NEDGE * 4);
    float* valsC1  = (float*)alloc(NEDGE * 4);
    float* valsC2  = (float*)alloc(NEDGE * 4);

    // U scratch lives in the second output copy (dead until cand epilogue)
    float* U = out + OUTHALF;

    uint4* Xb4 = (uint4*)Xb;
    uint4* Xc4 = (uint4*)Xc;
    auto slab = [&](int m) { return Xb4 + (size_t)m * 144; };  // slab m base, node stride 720

    // CSR build (graph shared by both diff_convs)
    zero_counts_kernel<<<(NNODES + 255) / 256, 256, 0, stream>>>(counts1, counts2);
    hist_kernel<<<(NEDGE + 255) / 256, 256, 0, stream>>>(esrc, edst, counts1, counts2);
    scan_kernel<<<1, 1024, 0, stream>>>(counts1, rowptr1, cursor1);
    scan_kernel<<<1, 1024, 0, stream>>>(counts2, rowptr2, cursor2);
    scatter_kernel<<<(NEDGE + 255) / 256, 256, 0, stream>>>(esrc, edst, v1, v2,
                                                            cursor1, cursor2,
                                                            cols1, valsC1, cols2, valsC2);

    convert_w_kernel<<<(192 * KP2 + 255) / 256, 256, 0, stream>>>(Wg, Wc, WgT, WcT);
    build_x0_kernel<<<(NNODES * BATCH * 36 + 255) / 256, 256, 0, stream>>>(
        inputs, state, (uint*)Xb, (uint*)Xc);

    // diff_conv #1 diffusion: both graphs per dispatch (dual)
    spmm_dual<<<2 * NNODES, 128, 0, stream>>>(rowptr1, cols1, valsC1, slab(0),
                                              rowptr2, cols2, valsC2, slab(0), NSTR4,
                                              slab(0), NSTR4, slab(1), slab(3), NSTR4,
                                              1.f, 0.f);
    spmm_dual<<<2 * NNODES, 128, 0, stream>>>(rowptr1, cols1, valsC1, slab(1),
                                              rowptr2, cols2, valsC2, slab(3), NSTR4,
                                              slab(0), NSTR4, slab(2), slab(4), NSTR4,
                                              2.f, -1.f);

    // gate GEMM + sigmoid; writes U (in d_out scratch) and xc slab0 (r*state) into Xc
    gate_mfma<<<NNODES / GN, 256, 0, stream>>>(Xb, WgT, bg, state, U, Xc);

    // diff_conv #2 diffusion on xc (x0 := Xc, node stride 144 uint4)
    spmm_dual<<<2 * NNODES, 128, 0, stream>>>(rowptr1, cols1, valsC1, Xc4,
                                              rowptr2, cols2, valsC2, Xc4, XCS4,
                                              Xc4, XCS4, slab(1), slab(3), NSTR4,
                                              1.f, 0.f);
    spmm_dual<<<2 * NNODES, 128, 0, stream>>>(rowptr1, cols1, valsC1, slab(1),
                                              rowptr2, cols2, valsC2, slab(3), NSTR4,
                                              Xc4, XCS4, slab(2), slab(4), NSTR4,
                                              2.f, -1.f);

    // candidate GEMM + tanh + GRU update + duplicated output
    cand_mfma<<<NNODES / GN, 256, 0, stream>>>(Xb, Xc, WcT, bc, state, U, out);
}

// Round 12
// 575.369 us; speedup vs baseline: 1.5976x; 1.0198x over previous
//
#include <hip/hip_runtime.h>
#include <cstddef>
#include <cstdint>

#define NNODES 8192
#define BATCH  16
#define HID    64
#define NEDGE  131072
#define SN     524288   // NNODES * HID (per-batch state stride)
#define OUTHALF 8388608 // BATCH * SN
#define FP2    72       // padded per-slab feature dim (66 real + 6 zero); 72 = 9*8
#define SLABU  1152     // ushorts per (node, slab) = 16*72
#define NSTR   5760     // ushorts per node = 5*SLABU
#define NSTR4  720      // uint4 per node in Xb (5760 ushorts / 8 per uint4)
#define XCS4   144      // uint4 per node in Xc (slab0-only buffer, 1152/8)
#define KP2    384      // padded K' = 12 k-tiles of 32 (360 real + 24 zero)
#define GN     8        // nodes per GEMM block (1024 blocks; r4-measured best)

typedef __attribute__((ext_vector_type(8))) short bf16x8;
typedef __attribute__((ext_vector_type(4))) float f32x4;

static __device__ __forceinline__ float bf2f(ushort u) {
    union { uint32_t i; float f; } c; c.i = ((uint32_t)u) << 16; return c.f;
}
static __device__ __forceinline__ ushort f2bf(float f) {
    union { float f; uint32_t i; } c; c.f = f;
    uint32_t lsb = (c.i >> 16) & 1;
    return (ushort)((c.i + 0x7fffu + lsb) >> 16);
}

// ---------------- CSR construction ----------------

__global__ void zero_counts_kernel(int* __restrict__ c1, int* __restrict__ c2) {
    int i = blockIdx.x * 256 + threadIdx.x;
    if (i < NNODES) { c1[i] = 0; c2[i] = 0; }
}

__global__ void hist_kernel(const int* __restrict__ src, const int* __restrict__ dst,
                            int* __restrict__ c1, int* __restrict__ c2) {
    int e = blockIdx.x * 256 + threadIdx.x;
    if (e < NEDGE) {
        atomicAdd(&c1[src[e]], 1);
        atomicAdd(&c2[dst[e]], 1);
    }
}

__global__ __launch_bounds__(1024) void scan_kernel(const int* __restrict__ counts,
                                                    int* __restrict__ rowptr,
                                                    int* __restrict__ cursor) {
    __shared__ int sh[1024];
    int tid = threadIdx.x;
    int base = tid * 8;
    int local[8];
    int sum = 0;
#pragma unroll
    for (int j = 0; j < 8; ++j) { local[j] = counts[base + j]; sum += local[j]; }
    sh[tid] = sum;
    __syncthreads();
    for (int off = 1; off < 1024; off <<= 1) {
        int v = (tid >= off) ? sh[tid - off] : 0;
        __syncthreads();
        sh[tid] += v;
        __syncthreads();
    }
    int p = sh[tid] - sum;
#pragma unroll
    for (int j = 0; j < 8; ++j) {
        cursor[base + j] = p;
        p += local[j];
        rowptr[base + j + 1] = p;
    }
    if (tid == 0) rowptr[0] = 0;
}

__global__ void scatter_kernel(const int* __restrict__ src, const int* __restrict__ dst,
                               const float* __restrict__ v1, const float* __restrict__ v2,
                               int* __restrict__ cur1, int* __restrict__ cur2,
                               int* __restrict__ cols1, float* __restrict__ valsC1,
                               int* __restrict__ cols2, float* __restrict__ valsC2) {
    int e = blockIdx.x * 256 + threadIdx.x;
    if (e < NEDGE) {
        int r1 = src[e];
        int p1 = atomicAdd(&cur1[r1], 1);
        cols1[p1] = dst[e];
        valsC1[p1] = v1[e];
        int r2 = dst[e];
        int p2 = atomicAdd(&cur2[r2], 1);
        cols2[p2] = src[e];
        valsC2[p2] = v2[e];
    }
}

// -------- weight transpose + bf16 convert: W[k=f*5+m][C] -> WT[C][k'=m*72+f] --------

__global__ void convert_w_kernel(const float* __restrict__ Wg, const float* __restrict__ Wc,
                                 ushort* __restrict__ WgT, ushort* __restrict__ WcT) {
    int i = blockIdx.x * 256 + threadIdx.x;
    if (i >= 192 * KP2) return;
    int col = i / KP2, k2 = i - col * KP2;
    int m = k2 / FP2, f = k2 - m * FP2;
    bool valid = (m < 5) && (f < 66);
    int ko = f * 5 + m;
    if (col < 128) {
        WgT[col * KP2 + k2] = valid ? f2bf(Wg[ko * 128 + col]) : (ushort)0;
    } else {
        int c = col - 128;
        WcT[c * KP2 + k2] = valid ? f2bf(Wc[ko * 64 + c]) : (ushort)0;
    }
}

// -------- build x0 (bf16): Xb[n][m=0][b][72], and Xc[n][b][72] input/pad parts --------

__global__ void build_x0_kernel(const float* __restrict__ inputs, const float* __restrict__ state,
                                uint* __restrict__ Xb_u, uint* __restrict__ Xc_u) {
    int t = blockIdx.x * 256 + threadIdx.x;
    if (t >= NNODES * BATCH * 36) return;
    int n = t / 576;           // 576 = 16*36 uints per node-slab
    int r = t - n * 576;       // b*36 + j
    int b = r / 36;
    int j = r - b * 36;
    int f0 = 2 * j;
    uint val = 0;
    if (f0 == 0) {
        float v0 = inputs[(size_t)b * (NNODES * 2) + n * 2 + 0];
        float v1 = inputs[(size_t)b * (NNODES * 2) + n * 2 + 1];
        val = (uint)f2bf(v0) | ((uint)f2bf(v1) << 16);
    } else if (f0 < 66) {
        float v0 = state[(size_t)b * SN + n * HID + (f0 - 2)];
        float v1 = state[(size_t)b * SN + n * HID + (f0 - 1)];
        val = (uint)f2bf(v0) | ((uint)f2bf(v1) << 16);
    }
    Xb_u[(size_t)n * 2880 + r] = val;               // slab0 = first 576 uints of node
    if (f0 == 0 || f0 >= 66) Xc_u[t] = val;         // inputs + zero pads of xc slab0
}

// ---------------- SPMM (bf16 rows, fp32 accumulate), 8-wide PREDICATED, dual-graph ----------------
// r11 engine + one change: single predicated loop stepping 8 edges (no scalar
// remainder). Off-row slots clamp to cols[s] with v=0 -> their gathers are
// L1-hits on the row already fetched in iter 1. MLP: 8 gathers in flight per
// main lane (was 4 + a serial scalar tail). Cached stores (r10 lesson:
// downstream GEMM reads the produced slabs from L2).

static __device__ __forceinline__ void fma8(float* acc, uint4 d, float v) {
    acc[0] += v * bf2f((ushort)(d.x));  acc[1] += v * bf2f((ushort)(d.x >> 16));
    acc[2] += v * bf2f((ushort)(d.y));  acc[3] += v * bf2f((ushort)(d.y >> 16));
    acc[4] += v * bf2f((ushort)(d.z));  acc[5] += v * bf2f((ushort)(d.z >> 16));
    acc[6] += v * bf2f((ushort)(d.w));  acc[7] += v * bf2f((ushort)(d.w >> 16));
}

static __device__ __forceinline__ uint4 blend_pack8(const float* acc, uint4 p,
                                                    float alpha, float beta) {
    float o[8];
    o[0] = alpha * acc[0] + beta * bf2f((ushort)(p.x));
    o[1] = alpha * acc[1] + beta * bf2f((ushort)(p.x >> 16));
    o[2] = alpha * acc[2] + beta * bf2f((ushort)(p.y));
    o[3] = alpha * acc[3] + beta * bf2f((ushort)(p.y >> 16));
    o[4] = alpha * acc[4] + beta * bf2f((ushort)(p.z));
    o[5] = alpha * acc[5] + beta * bf2f((ushort)(p.z >> 16));
    o[6] = alpha * acc[6] + beta * bf2f((ushort)(p.w));
    o[7] = alpha * acc[7] + beta * bf2f((ushort)(p.w >> 16));
    uint4 r;
    r.x = (uint32_t)f2bf(o[0]) | ((uint32_t)f2bf(o[1]) << 16);
    r.y = (uint32_t)f2bf(o[2]) | ((uint32_t)f2bf(o[3]) << 16);
    r.z = (uint32_t)f2bf(o[4]) | ((uint32_t)f2bf(o[5]) << 16);
    r.w = (uint32_t)f2bf(o[6]) | ((uint32_t)f2bf(o[7]) << 16);
    return r;
}

// row = 144 uint4 (2304 B) per (node, slab). strides in uint4 units.
// blocks [0,8192): graph 1; [8192,16384): graph 2. Both halves share xp/alpha/beta.
__global__ __launch_bounds__(128) void spmm_dual(
        const int* __restrict__ rp1, const int* __restrict__ c1, const float* __restrict__ v1,
        const uint4* __restrict__ x1,
        const int* __restrict__ rp2, const int* __restrict__ c2, const float* __restrict__ v2,
        const uint4* __restrict__ x2,
        int xs,
        const uint4* __restrict__ xp, int ps,
        uint4* __restrict__ y1, uint4* __restrict__ y2, int ys,
        float alpha, float beta) {
    int bid = blockIdx.x;
    int half = bid >> 13;
    int n = bid & 8191;
    const int* rowptr = half ? rp2 : rp1;
    const int* cols   = half ? c2 : c1;
    const float* vals = half ? v2 : v1;
    const uint4* x    = half ? x2 : x1;
    uint4* y          = half ? y2 : y1;

    int t = threadIdx.x;
    int s = rowptr[n], e = rowptr[n + 1];
    float a0[8] = {0, 0, 0, 0, 0, 0, 0, 0};
    float a1[8] = {0, 0, 0, 0, 0, 0, 0, 0};
    bool tail = t < 16;         // 144 chunks: t and (t<16 ? 128+t)
    int t2 = 128 + t;
    for (int i = s; i < e; i += 8) {
        int   c[8];
        float v[8];
#pragma unroll
        for (int k = 0; k < 8; ++k) {
            int ii = i + k;
            bool ok = ii < e;
            int idx = ok ? ii : s;      // clamp: row non-empty here (i<e)
            c[k] = cols[idx];
            v[k] = ok ? vals[idx] : 0.f;
        }
        uint4 d[8];
#pragma unroll
        for (int k = 0; k < 8; ++k) d[k] = x[(size_t)c[k] * xs + t];
        uint4 d2[8];
        if (tail) {
#pragma unroll
            for (int k = 0; k < 8; ++k) d2[k] = x[(size_t)c[k] * xs + t2];
        }
#pragma unroll
        for (int k = 0; k < 8; ++k) fma8(a0, d[k], v[k]);
        if (tail) {
#pragma unroll
            for (int k = 0; k < 8; ++k) fma8(a1, d2[k], v[k]);
        }
    }
    uint4* yb = y + (size_t)n * ys;
    const uint4* xpb = xp + (size_t)n * ps;
    uint4 p0 = (beta != 0.f) ? xpb[t] : make_uint4(0, 0, 0, 0);
    yb[t] = blend_pack8(a0, p0, alpha, beta);
    if (tail) {
        uint4 p1 = (beta != 0.f) ? xpb[t2] : make_uint4(0, 0, 0, 0);
        yb[t2] = blend_pack8(a1, p1, alpha, beta);
    }
}

// ---------------- gate GEMM: direct-global MFMA fragments, no LDS, no barriers ----------------
// r4 config exactly (measured 71 us): GN=8, (256,2), VGPR 76, no spill.

__global__ __launch_bounds__(256, 2) void gate_mfma(const ushort* __restrict__ Xb,
                                                    const ushort* __restrict__ WgT,
                                                    const float* __restrict__ bg,
                                                    const float* __restrict__ state,
                                                    float* __restrict__ U,
                                                    ushort* __restrict__ Xc) {
    int tid = threadIdx.x;
    int wave = tid >> 6, lane = tid & 63;
    int row = lane & 15, quad = lane >> 4;
    int c0 = wave * 32 + row;
    int c1 = c0 + 16;

    bf16x8 w0[12], w1[12];
#pragma unroll
    for (int kt = 0; kt < 12; ++kt) {
        w0[kt] = *(const bf16x8*)(WgT + (size_t)c0 * KP2 + kt * 32 + quad * 8);
        w1[kt] = *(const bf16x8*)(WgT + (size_t)c1 * KP2 + kt * 32 + quad * 8);
    }
    float bias0 = bg[c0], bias1 = bg[c1];

    // per-lane A-fragment offsets (ushort units): k' = 8*(4*kt+quad) = m*72+f0
    int offA[11];
#pragma unroll
    for (int kt = 0; kt < 11; ++kt) {
        int j = 4 * kt + quad;
        int m = j / 9;
        int f0 = 8 * (j - 9 * m);
        offA[kt] = m * SLABU + row * FP2 + f0;
    }
    int off11 = 4 * SLABU + row * FP2 + 64;  // kt=11, quad 0 only (k' 352..359)

    int nodeBase = blockIdx.x * GN;
    for (int g = 0; g < GN; ++g) {
        int n = nodeBase + g;
        const ushort* An = Xb + (size_t)n * NSTR;
        f32x4 acc0 = {0.f, 0.f, 0.f, 0.f};
        f32x4 acc1 = {0.f, 0.f, 0.f, 0.f};
#pragma unroll
        for (int kt = 0; kt < 11; ++kt) {
            bf16x8 av = *(const bf16x8*)(An + offA[kt]);
            acc0 = __builtin_amdgcn_mfma_f32_16x16x32_bf16(av, w0[kt], acc0, 0, 0, 0);
            acc1 = __builtin_amdgcn_mfma_f32_16x16x32_bf16(av, w1[kt], acc1, 0, 0, 0);
        }
        {
            bf16x8 av = {0, 0, 0, 0, 0, 0, 0, 0};
            if (quad == 0) av = *(const bf16x8*)(An + off11);
            acc0 = __builtin_amdgcn_mfma_f32_16x16x32_bf16(av, w0[11], acc0, 0, 0, 0);
            acc1 = __builtin_amdgcn_mfma_f32_16x16x32_bf16(av, w1[11], acc1, 0, 0, 0);
        }
        // D: col = lane&15 (-> c0/c1), row b = quad*4 + reg
#pragma unroll
        for (int r = 0; r < 4; ++r) {
            int b = quad * 4 + r;
            float v0 = 1.f / (1.f + __expf(-(acc0[r] + bias0)));
            float v1 = 1.f / (1.f + __expf(-(acc1[r] + bias1)));
            if (wave < 2) {  // cols 0..63: r-gate -> xc state part (bf16, separate buffer)
                float s0 = state[(size_t)b * SN + n * HID + c0];
                float s1 = state[(size_t)b * SN + n * HID + c1];
                Xc[(size_t)n * SLABU + b * FP2 + 2 + c0] = f2bf(v0 * s0);
                Xc[(size_t)n * SLABU + b * FP2 + 2 + c1] = f2bf(v1 * s1);
            } else {         // cols 64..127: u-gate (fp32)
                U[(size_t)b * SN + n * HID + (c0 - HID)] = v0;
                U[(size_t)b * SN + n * HID + (c1 - HID)] = v1;
            }
        }
    }
}

// ---------------- candidate GEMM + tanh + GRU update + output ----------------
// NOTE: U aliases out+OUTHALF (scratch in d_out) -> NO __restrict__ on U/out here.

__global__ __launch_bounds__(256, 3) void cand_mfma(const ushort* __restrict__ Xb,
                                                    const ushort* __restrict__ Xc,
                                                    const ushort* __restrict__ WcT,
                                                    const float* __restrict__ bc,
                                                    const float* __restrict__ state,
                                                    const float* U,
                                                    float* out) {
    int tid = threadIdx.x;
    int wave = tid >> 6, lane = tid & 63;
    int row = lane & 15, quad = lane >> 4;
    int c = wave * 16 + row;

    bf16x8 w[12];
#pragma unroll
    for (int kt = 0; kt < 12; ++kt)
        w[kt] = *(const bf16x8*)(WcT + (size_t)c * KP2 + kt * 32 + quad * 8);
    float bias = bc[c];

    int offA[11];
#pragma unroll
    for (int kt = 0; kt < 11; ++kt) {
        int j = 4 * kt + quad;
        int m = j / 9;
        int f0 = 8 * (j - 9 * m);
        offA[kt] = m * SLABU + row * FP2 + f0;  // m==0 offsets are also Xc-relative
    }
    int off11 = 4 * SLABU + row * FP2 + 64;

    int nodeBase = blockIdx.x * GN;
    for (int g = 0; g < GN; ++g) {
        int n = nodeBase + g;
        const ushort* AnB = Xb + (size_t)n * NSTR;
        const ushort* AnC = Xc + (size_t)n * SLABU;
        f32x4 acc = {0.f, 0.f, 0.f, 0.f};
#pragma unroll
        for (int kt = 0; kt < 11; ++kt) {
            // kt 0,1: pure slab0 (Xc). kt 2: quad0 -> Xc, quads 1..3 -> Xb slab1. kt>=3: Xb.
            const ushort* bp = (kt < 2) ? AnC
                             : (kt == 2 ? (quad == 0 ? AnC : AnB) : AnB);
            bf16x8 av = *(const bf16x8*)(bp + offA[kt]);
            acc = __builtin_amdgcn_mfma_f32_16x16x32_bf16(av, w[kt], acc, 0, 0, 0);
        }
        {
            bf16x8 av = {0, 0, 0, 0, 0, 0, 0, 0};
            if (quad == 0) av = *(const bf16x8*)(AnB + off11);
            acc = __builtin_amdgcn_mfma_f32_16x16x32_bf16(av, w[11], acc, 0, 0, 0);
        }
#pragma unroll
        for (int r = 0; r < 4; ++r) {
            int b = quad * 4 + r;
            float pre = acc[r] + bias;
            float cv = 1.f - 2.f / (__expf(2.f * pre) + 1.f);  // tanh
            size_t idx = (size_t)b * SN + n * HID + c;
            float uv = U[idx];       // read BEFORE the aliased write below
            float s = state[idx];
            float ns = uv * s + (1.f - uv) * cv;
            out[idx] = ns;
            out[OUTHALF + idx] = ns; // overwrites U[idx] (same thread, after read)
        }
    }
}

// ---------------- launch ----------------

extern "C" void kernel_launch(void* const* d_in, const int* in_sizes, int n_in,
                              void* d_out, int out_size, void* d_ws, size_t ws_size,
                              hipStream_t stream) {
    const float* inputs = (const float*)d_in[0];
    const float* state  = (const float*)d_in[1];
    const int*   esrc   = (const int*)d_in[2];
    const int*   edst   = (const int*)d_in[3];
    const float* v1     = (const float*)d_in[4];
    const float* v2     = (const float*)d_in[5];
    const float* Wg     = (const float*)d_in[6];
    const float* bg     = (const float*)d_in[7];
    const float* Wc     = (const float*)d_in[8];
    const float* bc     = (const float*)d_in[9];
    float* out = (float*)d_out;

    char* ws = (char*)d_ws;
    size_t off = 0;
    auto alloc = [&](size_t bytes) -> void* {
        void* p = ws + off;
        off += (bytes + 255) & ~(size_t)255;
        return p;
    };
    ushort* Xb     = (ushort*)alloc((size_t)NNODES * NSTR * 2);   // 94.4 MB [n][m][b][72]
    ushort* Xc     = (ushort*)alloc((size_t)NNODES * SLABU * 2);  // 18.9 MB xc slab0
    ushort* WgT    = (ushort*)alloc((size_t)128 * KP2 * 2);
    ushort* WcT    = (ushort*)alloc((size_t)64 * KP2 * 2);
    int*   counts1 = (int*)alloc(NNODES * 4);
    int*   counts2 = (int*)alloc(NNODES * 4);
    int*   rowptr1 = (int*)alloc((NNODES + 1) * 4);
    int*   rowptr2 = (int*)alloc((NNODES + 1) * 4);
    int*   cursor1 = (int*)alloc(NNODES * 4);
    int*   cursor2 = (int*)alloc(NNODES * 4);
    int*   cols1   = (int*)alloc(NEDGE * 4);
    int*   cols2   = (int*)alloc(NEDGE * 4);
    float* valsC1  = (float*)alloc(NEDGE * 4);
    float* valsC2  = (float*)alloc(NEDGE * 4);

    // U scratch lives in the second output copy (dead until cand epilogue)
    float* U = out + OUTHALF;

    uint4* Xb4 = (uint4*)Xb;
    uint4* Xc4 = (uint4*)Xc;
    auto slab = [&](int m) { return Xb4 + (size_t)m * 144; };  // slab m base, node stride 720

    // CSR build (graph shared by both diff_convs)
    zero_counts_kernel<<<(NNODES + 255) / 256, 256, 0, stream>>>(counts1, counts2);
    hist_kernel<<<(NEDGE + 255) / 256, 256, 0, stream>>>(esrc, edst, counts1, counts2);
    scan_kernel<<<1, 1024, 0, stream>>>(counts1, rowptr1, cursor1);
    scan_kernel<<<1, 1024, 0, stream>>>(counts2, rowptr2, cursor2);
    scatter_kernel<<<(NEDGE + 255) / 256, 256, 0, stream>>>(esrc, edst, v1, v2,
                                                            cursor1, cursor2,
                                                            cols1, valsC1, cols2, valsC2);

    convert_w_kernel<<<(192 * KP2 + 255) / 256, 256, 0, stream>>>(Wg, Wc, WgT, WcT);
    build_x0_kernel<<<(NNODES * BATCH * 36 + 255) / 256, 256, 0, stream>>>(
        inputs, state, (uint*)Xb, (uint*)Xc);

    // diff_conv #1 diffusion: both graphs per dispatch (dual)
    spmm_dual<<<2 * NNODES, 128, 0, stream>>>(rowptr1, cols1, valsC1, slab(0),
                                              rowptr2, cols2, valsC2, slab(0), NSTR4,
                                              slab(0), NSTR4, slab(1), slab(3), NSTR4,
                                              1.f, 0.f);
    spmm_dual<<<2 * NNODES, 128, 0, stream>>>(rowptr1, cols1, valsC1, slab(1),
                                              rowptr2, cols2, valsC2, slab(3), NSTR4,
                                              slab(0), NSTR4, slab(2), slab(4), NSTR4,
                                              2.f, -1.f);

    // gate GEMM + sigmoid; writes U (in d_out scratch) and xc slab0 (r*state) into Xc
    gate_mfma<<<NNODES / GN, 256, 0, stream>>>(Xb, WgT, bg, state, U, Xc);

    // diff_conv #2 diffusion on xc (x0 := Xc, node stride 144 uint4)
    spmm_dual<<<2 * NNODES, 128, 0, stream>>>(rowptr1, cols1, valsC1, Xc4,
                                              rowptr2, cols2, valsC2, Xc4, XCS4,
                                              Xc4, XCS4, slab(1), slab(3), NSTR4,
                                              1.f, 0.f);
    spmm_dual<<<2 * NNODES, 128, 0, stream>>>(rowptr1, cols1, valsC1, slab(1),
                                              rowptr2, cols2, valsC2, slab(3), NSTR4,
                                              Xc4, XCS4, slab(2), slab(4), NSTR4,
                                              2.f, -1.f);

    // candidate GEMM + tanh + GRU update + duplicated output
    cand_mfma<<<NNODES / GN, 256, 0, stream>>>(Xb, Xc, WcT, bc, state, U, out);
}